// Round 1
// baseline (7006.702 us; speedup 1.0000x reference)
//
#include <hip/hip_runtime.h>
#include <hip/hip_fp16.h>

// ---------------- constants (fixed by setup_inputs) ----------------
#define LAYERS 4
#define NH 16
#define KVH 4
#define HD 128
#define Hdim 2048          // NH*HD
#define FF 8192
#define VOCAB 32000
#define GQA 4              // NH/KVH
#define Tq 256             // ids_len
#define HIST 1024
#define KVLEN 1280         // HIST + Tq
#define EPS 1e-6f
#define SCALE_FACTOR 0.29730177875068026f  // 128^-0.25

// ---------------- generic tiled fp32 GEMM: C[M,N] = A[M,K] @ B[K,N] (+RES) ----
// Requires M%64==0, N%64==0, K%16==0. Batched via grid.z with strides; B batch
// index is z / bdivB (for GQA head sharing).
#define GT 64
#define GKT 16
__global__ __launch_bounds__(256) void gemm_f32(
    const float* __restrict__ A, int lda, long long sA,
    const float* __restrict__ B, int ldb, long long sB, int bdivB,
    float* __restrict__ C, int ldc, long long sC,
    const float* __restrict__ RES, int ldres,
    int M, int N, int K)
{
    const int z = blockIdx.z;
    A += (long long)z * sA;
    B += (long long)(z / bdivB) * sB;
    C += (long long)z * sC;

    __shared__ float As[GKT][GT];   // As[k][m]
    __shared__ float Bs[GKT][GT];   // Bs[k][n]

    const int tid = threadIdx.x;
    const int m0 = blockIdx.y * GT;
    const int n0 = blockIdx.x * GT;

    const int ar = tid >> 2;          // 0..63 (A row within tile)
    const int ak = (tid & 3) * 4;     // 0..12 (A k-offset)
    const int bk = tid >> 4;          // 0..15 (B k-row)
    const int bn = (tid & 15) * 4;    // 0..60 (B n-offset)

    const int tr = tid >> 4;          // 0..15
    const int tc = tid & 15;          // 0..15

    float acc[4][4] = {};

    for (int k0 = 0; k0 < K; k0 += GKT) {
        const float4 av = *reinterpret_cast<const float4*>(
            &A[(long long)(m0 + ar) * lda + k0 + ak]);
        const float4 bv = *reinterpret_cast<const float4*>(
            &B[(long long)(k0 + bk) * ldb + n0 + bn]);
        __syncthreads();
        As[ak + 0][ar] = av.x;
        As[ak + 1][ar] = av.y;
        As[ak + 2][ar] = av.z;
        As[ak + 3][ar] = av.w;
        *reinterpret_cast<float4*>(&Bs[bk][bn]) = bv;
        __syncthreads();
#pragma unroll
        for (int kk = 0; kk < GKT; ++kk) {
            float a[4], b[4];
#pragma unroll
            for (int i = 0; i < 4; ++i) a[i] = As[kk][tr * 4 + i];
#pragma unroll
            for (int j = 0; j < 4; ++j) b[j] = Bs[kk][tc * 4 + j];
#pragma unroll
            for (int i = 0; i < 4; ++i)
#pragma unroll
                for (int j = 0; j < 4; ++j)
                    acc[i][j] = fmaf(a[i], b[j], acc[i][j]);
        }
    }
#pragma unroll
    for (int i = 0; i < 4; ++i) {
        const int m = m0 + tr * 4 + i;
#pragma unroll
        for (int j = 0; j < 4; ++j) {
            const int n = n0 + tc * 4 + j;
            float v = acc[i][j];
            if (RES) v += RES[(long long)m * ldres + n];
            C[(long long)m * ldc + n] = v;
        }
    }
}

// ---------------- embedding dequant ----------------
__global__ __launch_bounds__(256) void embed_k(
    const int* __restrict__ ids, const int* __restrict__ eq,
    const float* __restrict__ es, const float* __restrict__ ez,
    float* __restrict__ h)
{
    const int t = blockIdx.x;
    const int id = ids[t];
    const float sc = es[id];
    const float zp = ez[id];
    const int* row = eq + (long long)id * Hdim;
    float* hr = h + (long long)t * Hdim;
    for (int c = threadIdx.x; c < Hdim; c += 256)
        hr[c] = (float)row[c] * sc + zp;
}

// ---------------- RMSNorm over rows of width W ----------------
__global__ __launch_bounds__(256) void rmsnorm_k(
    const float* __restrict__ x, const float* __restrict__ w,
    float* __restrict__ o, int W)
{
    const int row = blockIdx.x;
    const float* xr = x + (long long)row * W;
    float* orow = o + (long long)row * W;
    float ss = 0.f;
    for (int c = threadIdx.x; c < W; c += 256) { float v = xr[c]; ss += v * v; }
    __shared__ float red[256];
    red[threadIdx.x] = ss;
    __syncthreads();
    for (int s = 128; s > 0; s >>= 1) {
        if (threadIdx.x < s) red[threadIdx.x] += red[threadIdx.x + s];
        __syncthreads();
    }
    const float inv = 1.0f / sqrtf(red[0] / (float)W + EPS);
    for (int c = threadIdx.x; c < W; c += 256) orow[c] = xr[c] * inv * w[c];
}

// ---------------- RoPE + per-head RMS for q and k ----------------
// grid: (NH+KVH, Tq), 128 threads. q -> q_r [NH,Tq,HD]; k -> nk layer base
// [KVH, HD, KVLEN] at column HIST+t (transposed store).
__global__ __launch_bounds__(128) void rope_k(
    const float* __restrict__ qbuf,   // [Tq, Hdim]
    const float* __restrict__ kbuf,   // [Tq, KVH*HD]
    const float* __restrict__ q_ln,   // [HD]
    const float* __restrict__ k_ln,   // [HD]
    float* __restrict__ q_r,          // [NH, Tq, HD]
    float* __restrict__ nk)           // layer base of out nk: [KVH, HD, KVLEN]
{
    const int t = blockIdx.y;
    const int head = blockIdx.x;      // 0..NH+KVH-1
    const int d = threadIdx.x;        // 0..127
    const bool isq = head < NH;
    const float* in = isq ? &qbuf[(long long)t * Hdim + head * HD]
                          : &kbuf[(long long)t * (KVH * HD) + (head - NH) * HD];
    __shared__ float row[HD];
    row[d] = in[d];
    __syncthreads();
    const int j = d & 63;
    const float e = (float)j * (2.0f / 128.0f);
    const float inv_freq = 1.0f / powf(10000.0f, e);
    const float ang = (float)(HIST + t) * inv_freq;
    const float c = __half2float(__float2half(cosf(ang)));
    const float s = __half2float(__float2half(sinf(ang)));
    const float other = (d < 64) ? -row[d + 64] : row[d - 64];
    const float r = row[d] * c + other * s;
    __shared__ float red[HD];
    red[d] = r * r;
    __syncthreads();
    for (int st = 64; st > 0; st >>= 1) {
        if (d < st) red[d] += red[d + st];
        __syncthreads();
    }
    const float inv = 1.0f / sqrtf(red[0] / (float)HD + EPS);
    const float wv = (isq ? q_ln[d] : k_ln[d]) * SCALE_FACTOR;
    const float outv = r * inv * wv;
    if (isq) {
        q_r[((long long)head * Tq + t) * HD + d] = outv;
    } else {
        const int jh = head - NH;
        nk[((long long)jh * HD + d) * KVLEN + (HIST + t)] = outv;
    }
}

// ---------------- cache copies into outputs ----------------
__global__ __launch_bounds__(256) void kcache_copy_k(
    const float* __restrict__ kc, float* __restrict__ nk)
{
    const long long i = (long long)blockIdx.x * 256 + threadIdx.x; // < L*KVH*HD*HIST
    const long long row = i >> 10;       // /HIST
    const int c = (int)(i & 1023);
    nk[row * KVLEN + c] = kc[i];
}
__global__ __launch_bounds__(256) void vcache_copy_k(
    const float* __restrict__ vc, float* __restrict__ nv)
{
    const long long i = (long long)blockIdx.x * 256 + threadIdx.x; // < L*KVH*HIST*HD
    const long long chunk = i / (HIST * HD);
    const long long off = i % (HIST * HD);
    nv[chunk * (long long)(KVLEN * HD) + off] = vc[i];
}
// new v rows into nv layer base [KVH, KVLEN, HD]
__global__ __launch_bounds__(256) void vnew_copy_k(
    const float* __restrict__ vbuf, float* __restrict__ nv)
{
    const int i = blockIdx.x * 256 + threadIdx.x;   // < Tq*KVH*HD
    const int t = i >> 9;
    const int rem = i & 511;
    const int j = rem >> 7;
    const int d = rem & 127;
    nv[((long long)j * KVLEN + HIST + t) * HD + d] = vbuf[i];
}

// ---------------- mask + softmax over score rows ----------------
// grid: (Tq, NH); row length KVLEN, 256 threads -> 5 cols/thread
__global__ __launch_bounds__(256) void softmax_k(
    float* __restrict__ scores, const float* __restrict__ flagp)
{
    const int t = blockIdx.x;
    const int hh = blockIdx.y;
    float* row = scores + ((long long)hh * Tq + t) * KVLEN;
    const float maskv = -128.0f * flagp[0];
    float vals[5];
    float m = -INFINITY;
#pragma unroll
    for (int ii = 0; ii < 5; ++ii) {
        const int c = threadIdx.x + ii * 256;
        float v = row[c] + ((c <= t) ? 0.0f : maskv);
        vals[ii] = v;
        m = fmaxf(m, v);
    }
    __shared__ float red[256];
    red[threadIdx.x] = m;
    __syncthreads();
    for (int s = 128; s > 0; s >>= 1) {
        if (threadIdx.x < s) red[threadIdx.x] = fmaxf(red[threadIdx.x], red[threadIdx.x + s]);
        __syncthreads();
    }
    const float M = red[0];
    __syncthreads();
    float sum = 0.f;
#pragma unroll
    for (int ii = 0; ii < 5; ++ii) {
        const float ev = expf(vals[ii] - M);
        vals[ii] = ev;
        sum += ev;
    }
    red[threadIdx.x] = sum;
    __syncthreads();
    for (int s = 128; s > 0; s >>= 1) {
        if (threadIdx.x < s) red[threadIdx.x] += red[threadIdx.x + s];
        __syncthreads();
    }
    const float invS = 1.0f / red[0];
#pragma unroll
    for (int ii = 0; ii < 5; ++ii)
        row[threadIdx.x + ii * 256] = vals[ii] * invS;
}

// ---------------- SwiGLU elementwise ----------------
__global__ __launch_bounds__(256) void swiglu_k(
    float* __restrict__ gate, const float* __restrict__ up, long long n)
{
    const long long i = (long long)blockIdx.x * 256 + threadIdx.x;
    if (i < n) {
        const float g = gate[i];
        const float si = g / (1.0f + expf(-g));
        gate[i] = si * up[i];
    }
}

// ---------------- lm_head GEMV: logits[VOCAB] = hl[Hdim] @ W[Hdim,VOCAB] ----
__global__ __launch_bounds__(256) void lmhead_k(
    const float* __restrict__ hl, const float* __restrict__ W,
    float* __restrict__ logits)
{
    __shared__ float s_hl[Hdim];
    for (int k = threadIdx.x; k < Hdim; k += 256) s_hl[k] = hl[k];
    __syncthreads();
    const int col = blockIdx.x * 64 + (threadIdx.x & 63);
    const int kp = threadIdx.x >> 6;  // 0..3
    float acc = 0.f;
    for (int k = kp; k < Hdim; k += 4)
        acc = fmaf(s_hl[k], W[(long long)k * VOCAB + col], acc);
    __shared__ float red[256];
    red[threadIdx.x] = acc;
    __syncthreads();
    if (kp == 0)
        logits[col] = red[threadIdx.x] + red[threadIdx.x + 64] +
                      red[threadIdx.x + 128] + red[threadIdx.x + 192];
}

// ---------------- argmax (first-max tie-break) + KV scalar ----------------
__global__ __launch_bounds__(256) void argmax_k(
    const float* __restrict__ logits, float* __restrict__ out_tok,
    float* __restrict__ out_kv)
{
    float best = -INFINITY;
    int bi = 0x7fffffff;
    for (int c = threadIdx.x; c < VOCAB; c += 256) {
        const float v = logits[c];
        if (v > best) { best = v; bi = c; }
    }
    __shared__ float bv[256];
    __shared__ int bidx[256];
    bv[threadIdx.x] = best;
    bidx[threadIdx.x] = bi;
    __syncthreads();
    for (int s = 128; s > 0; s >>= 1) {
        if (threadIdx.x < s) {
            const float ov = bv[threadIdx.x + s];
            const int oi = bidx[threadIdx.x + s];
            if (ov > bv[threadIdx.x] ||
                (ov == bv[threadIdx.x] && oi < bidx[threadIdx.x])) {
                bv[threadIdx.x] = ov;
                bidx[threadIdx.x] = oi;
            }
        }
        __syncthreads();
    }
    if (threadIdx.x == 0) {
        out_tok[0] = (float)bidx[0];
        out_kv[0] = (float)KVLEN;
    }
}

// =======================================================================
extern "C" void kernel_launch(void* const* d_in, const int* in_sizes, int n_in,
                              void* d_out, int out_size, void* d_ws, size_t ws_size,
                              hipStream_t stream)
{
    // inputs (setup_inputs order)
    const int*   input_ids   = (const int*)  d_in[0];
    const float* key_cache   = (const float*)d_in[1];
    const float* value_cache = (const float*)d_in[2];
    const float* attn_flag   = (const float*)d_in[3];
    const int*   embed_q     = (const int*)  d_in[6];
    const float* embed_scale = (const float*)d_in[7];
    const float* embed_zp    = (const float*)d_in[8];
    const float* in_ln_w     = (const float*)d_in[9];
    const float* wq          = (const float*)d_in[10];
    const float* wk          = (const float*)d_in[11];
    const float* wv          = (const float*)d_in[12];
    const float* wo          = (const float*)d_in[13];
    const float* q_ln_w      = (const float*)d_in[14];
    const float* k_ln_w      = (const float*)d_in[15];
    const float* post_ln_w   = (const float*)d_in[16];
    const float* w_gate      = (const float*)d_in[17];
    const float* w_up        = (const float*)d_in[18];
    const float* w_down      = (const float*)d_in[19];
    const float* final_norm_w= (const float*)d_in[20];
    const float* lm_head_w   = (const float*)d_in[21];

    // outputs (flat fp32): nk | nv | token | kv
    float* out_nk = (float*)d_out;
    float* out_nv = out_nk + (long long)LAYERS * KVH * HD * KVLEN;
    float* out_tok = out_nv + (long long)LAYERS * KVH * KVLEN * HD;
    float* out_kv = out_tok + 1;

    // workspace layout (floats)
    float* ws = (float*)d_ws;
    float* h        = ws;                       // Tq*Hdim = 524288
    float* hn       = h + 524288;               // 524288
    float* qbuf     = hn + 524288;              // 524288
    float* q_r      = qbuf + 524288;            // 524288
    float* kbuf     = q_r + 524288;             // 131072
    float* vbuf     = kbuf + 131072;            // 131072
    float* attn_out = vbuf + 131072;            // 524288
    float* scores   = attn_out + 524288;        // NH*Tq*KVLEN = 5242880
    float* gate     = scores;                   // reuse (after attnv)
    float* up       = scores + 2097152;         // reuse
    float* hl       = scores + 5242880;         // 2048
    float* logits   = hl + 2048;                // 32000

    dim3 b256(256);

    // embed -> h
    embed_k<<<dim3(Tq), b256, 0, stream>>>(input_ids, embed_q, embed_scale, embed_zp, h);

    // copy caches into outputs (cols 0..HIST-1 / rows 0..HIST-1)
    {
        const long long nk_tot = (long long)LAYERS * KVH * HD * HIST;  // 2097152
        kcache_copy_k<<<dim3((unsigned)((nk_tot + 255) / 256)), b256, 0, stream>>>(key_cache, out_nk);
        const long long nv_tot = (long long)LAYERS * KVH * HIST * HD;
        vcache_copy_k<<<dim3((unsigned)((nv_tot + 255) / 256)), b256, 0, stream>>>(value_cache, out_nv);
    }

    for (int l = 0; l < LAYERS; ++l) {
        const float* wq_l = wq + (long long)l * Hdim * Hdim;
        const float* wk_l = wk + (long long)l * Hdim * (KVH * HD);
        const float* wv_l = wv + (long long)l * Hdim * (KVH * HD);
        const float* wo_l = wo + (long long)l * Hdim * Hdim;
        const float* wg_l = w_gate + (long long)l * Hdim * FF;
        const float* wu_l = w_up + (long long)l * Hdim * FF;
        const float* wd_l = w_down + (long long)l * FF * Hdim;
        float* nk_l = out_nk + (long long)l * KVH * HD * KVLEN;
        float* nv_l = out_nv + (long long)l * KVH * KVLEN * HD;

        // hn = rms(h, in_ln_w[l])
        rmsnorm_k<<<dim3(Tq), b256, 0, stream>>>(h, in_ln_w + (long long)l * Hdim, hn, Hdim);

        // q/k/v projections
        gemm_f32<<<dim3(Hdim / GT, Tq / GT, 1), b256, 0, stream>>>(
            hn, Hdim, 0, wq_l, Hdim, 0, 1, qbuf, Hdim, 0, nullptr, 0, Tq, Hdim, Hdim);
        gemm_f32<<<dim3((KVH * HD) / GT, Tq / GT, 1), b256, 0, stream>>>(
            hn, Hdim, 0, wk_l, KVH * HD, 0, 1, kbuf, KVH * HD, 0, nullptr, 0, Tq, KVH * HD, Hdim);
        gemm_f32<<<dim3((KVH * HD) / GT, Tq / GT, 1), b256, 0, stream>>>(
            hn, Hdim, 0, wv_l, KVH * HD, 0, 1, vbuf, KVH * HD, 0, nullptr, 0, Tq, KVH * HD, Hdim);

        // rope + head-RMS; k written transposed into out nk
        rope_k<<<dim3(NH + KVH, Tq), dim3(128), 0, stream>>>(
            qbuf, kbuf, q_ln_w + (long long)l * HD, k_ln_w + (long long)l * HD, q_r, nk_l);

        // new v rows into out nv
        vnew_copy_k<<<dim3((Tq * KVH * HD) / 256), b256, 0, stream>>>(vbuf, nv_l);

        // scores[h] = q_r[h] (Tq x HD) @ nk[h/G] (HD x KVLEN)
        gemm_f32<<<dim3(KVLEN / GT, Tq / GT, NH), b256, 0, stream>>>(
            q_r, HD, (long long)Tq * HD,
            nk_l, KVLEN, (long long)HD * KVLEN, GQA,
            scores, KVLEN, (long long)Tq * KVLEN,
            nullptr, 0, Tq, KVLEN, HD);

        // mask + softmax
        softmax_k<<<dim3(Tq, NH), b256, 0, stream>>>(scores, attn_flag);

        // attn_out[:, h*HD:(h+1)*HD] = P[h] (Tq x KVLEN) @ nv[h/G] (KVLEN x HD)
        gemm_f32<<<dim3(HD / GT, Tq / GT, NH), b256, 0, stream>>>(
            scores, KVLEN, (long long)Tq * KVLEN,
            nv_l, HD, (long long)KVLEN * HD, GQA,
            attn_out, Hdim, (long long)HD,
            nullptr, 0, Tq, HD, KVLEN);

        // h = h + attn_out @ wo
        gemm_f32<<<dim3(Hdim / GT, Tq / GT, 1), b256, 0, stream>>>(
            attn_out, Hdim, 0, wo_l, Hdim, 0, 1, h, Hdim, 0, h, Hdim, Tq, Hdim, Hdim);

        // post-LN
        rmsnorm_k<<<dim3(Tq), b256, 0, stream>>>(h, post_ln_w + (long long)l * Hdim, hn, Hdim);

        // gate / up
        gemm_f32<<<dim3(FF / GT, Tq / GT, 1), b256, 0, stream>>>(
            hn, Hdim, 0, wg_l, FF, 0, 1, gate, FF, 0, nullptr, 0, Tq, FF, Hdim);
        gemm_f32<<<dim3(FF / GT, Tq / GT, 1), b256, 0, stream>>>(
            hn, Hdim, 0, wu_l, FF, 0, 1, up, FF, 0, nullptr, 0, Tq, FF, Hdim);

        // gate = silu(gate)*up
        swiglu_k<<<dim3((Tq * FF) / 256), b256, 0, stream>>>(gate, up, (long long)Tq * FF);

        // h = h + gate @ w_down
        gemm_f32<<<dim3(Hdim / GT, Tq / GT, 1), b256, 0, stream>>>(
            gate, FF, 0, wd_l, Hdim, 0, 1, h, Hdim, 0, h, Hdim, Tq, Hdim, FF);
    }

    // final norm on last token
    rmsnorm_k<<<dim3(1), b256, 0, stream>>>(h + (long long)(Tq - 1) * Hdim, final_norm_w, hl, Hdim);

    // logits + argmax
    lmhead_k<<<dim3(VOCAB / 64), b256, 0, stream>>>(hl, lm_head_w, logits);
    argmax_k<<<dim3(1), b256, 0, stream>>>(logits, out_tok, out_kv);
}

// Round 2
// 5199.958 us; speedup vs baseline: 1.3475x; 1.3475x over previous
//
#include <hip/hip_runtime.h>
#include <hip/hip_fp16.h>

// ---------------- constants (fixed by setup_inputs) ----------------
#define LAYERS 4
#define NH 16
#define KVH 4
#define HD 128
#define Hdim 2048          // NH*HD
#define FF 8192
#define VOCAB 32000
#define GQA 4              // NH/KVH
#define Tq 256             // ids_len
#define HIST 1024
#define KVLEN 1280         // HIST + Tq
#define EPS 1e-6f
#define SCALE_FACTOR 0.29730177875068026f  // 128^-0.25

typedef _Float16 h4 __attribute__((ext_vector_type(4)));
typedef _Float16 h8 __attribute__((ext_vector_type(8)));
typedef float f32x4 __attribute__((ext_vector_type(4)));

// ---------------- MFMA f16 GEMM: C[M,N] = A[M,K] @ B[K,N] (+RES) ----------
// A,B fp32 in HBM, converted to f16 during LDS staging. Tile 128x128, BK=32.
// 256 threads = 4 waves in 2x2, each wave computes 64x64 via 4x4 of
// mfma_f32_16x16x32_f16. Batched via grid.z (B index = z / bdivB for GQA).
#define BM 128
#define BN 128
#define BK 32
#define LDK 40   // padded f16 stride (80 B -> 2-way bank aliasing, free)

__global__ __launch_bounds__(256) void gemm_mfma(
    const float* __restrict__ A, int lda, long long sA,
    const float* __restrict__ B, int ldb, long long sB, int bdivB,
    float* __restrict__ C, int ldc, long long sC,
    const float* __restrict__ RES, int ldres,
    int K)
{
    const int z = blockIdx.z;
    A += (long long)z * sA;
    B += (long long)(z / bdivB) * sB;
    C += (long long)z * sC;

    __shared__ _Float16 As[BM * LDK];
    __shared__ _Float16 Bs[BN * LDK];

    const int t = threadIdx.x;
    const int m0 = blockIdx.y * BM;
    const int n0 = blockIdx.x * BN;

    // A staging coords: 2 threads per row, 16 floats each
    const int am = t >> 1;                 // 0..127
    const int ak0 = (t & 1) * 16;          // 0 or 16
    // B staging coords: 4x4 blocks; kb in 0..7, nb in 0..31
    const int kb = t >> 5;
    const int nb = t & 31;

    // compute coords
    const int w = t >> 6;                  // wave 0..3
    const int wr = (w >> 1) * 64;          // wave row offset
    const int wc = (w & 1) * 64;           // wave col offset
    const int lane = t & 63;
    const int lm = lane & 15;
    const int quad = lane >> 4;            // 0..3

    f32x4 acc[4][4] = {};

    for (int k0 = 0; k0 < K; k0 += BK) {
        // ---- global loads (fp32) ----
        const float* Ap = A + (long long)(m0 + am) * lda + k0 + ak0;
        const float4 a0 = *reinterpret_cast<const float4*>(Ap + 0);
        const float4 a1 = *reinterpret_cast<const float4*>(Ap + 4);
        const float4 a2 = *reinterpret_cast<const float4*>(Ap + 8);
        const float4 a3 = *reinterpret_cast<const float4*>(Ap + 12);

        const float* Bp = B + (long long)(k0 + kb * 4) * ldb + n0 + nb * 4;
        const float4 r0 = *reinterpret_cast<const float4*>(Bp);
        const float4 r1 = *reinterpret_cast<const float4*>(Bp + ldb);
        const float4 r2 = *reinterpret_cast<const float4*>(Bp + 2 * (long long)ldb);
        const float4 r3 = *reinterpret_cast<const float4*>(Bp + 3 * (long long)ldb);

        __syncthreads();   // all waves done reading LDS from previous tile

        // ---- convert + LDS writes ----
        {
            _Float16* dst = &As[am * LDK + ak0];
            h4 v0 = {(_Float16)a0.x, (_Float16)a0.y, (_Float16)a0.z, (_Float16)a0.w};
            h4 v1 = {(_Float16)a1.x, (_Float16)a1.y, (_Float16)a1.z, (_Float16)a1.w};
            h4 v2 = {(_Float16)a2.x, (_Float16)a2.y, (_Float16)a2.z, (_Float16)a2.w};
            h4 v3 = {(_Float16)a3.x, (_Float16)a3.y, (_Float16)a3.z, (_Float16)a3.w};
            *reinterpret_cast<h4*>(dst + 0)  = v0;
            *reinterpret_cast<h4*>(dst + 4)  = v1;
            *reinterpret_cast<h4*>(dst + 8)  = v2;
            *reinterpret_cast<h4*>(dst + 12) = v3;
        }
        {
            // transpose 4x4: Bs[n][k]
            h4 c0 = {(_Float16)r0.x, (_Float16)r1.x, (_Float16)r2.x, (_Float16)r3.x};
            h4 c1 = {(_Float16)r0.y, (_Float16)r1.y, (_Float16)r2.y, (_Float16)r3.y};
            h4 c2 = {(_Float16)r0.z, (_Float16)r1.z, (_Float16)r2.z, (_Float16)r3.z};
            h4 c3 = {(_Float16)r0.w, (_Float16)r1.w, (_Float16)r2.w, (_Float16)r3.w};
            const int kk = kb * 4;
            *reinterpret_cast<h4*>(&Bs[(nb * 4 + 0) * LDK + kk]) = c0;
            *reinterpret_cast<h4*>(&Bs[(nb * 4 + 1) * LDK + kk]) = c1;
            *reinterpret_cast<h4*>(&Bs[(nb * 4 + 2) * LDK + kk]) = c2;
            *reinterpret_cast<h4*>(&Bs[(nb * 4 + 3) * LDK + kk]) = c3;
        }
        __syncthreads();

        // ---- fragments + MFMA ----
        h8 af[4], bf[4];
#pragma unroll
        for (int i = 0; i < 4; ++i)
            af[i] = *reinterpret_cast<const h8*>(&As[(wr + i * 16 + lm) * LDK + quad * 8]);
#pragma unroll
        for (int j = 0; j < 4; ++j)
            bf[j] = *reinterpret_cast<const h8*>(&Bs[(wc + j * 16 + lm) * LDK + quad * 8]);
#pragma unroll
        for (int i = 0; i < 4; ++i)
#pragma unroll
            for (int j = 0; j < 4; ++j)
                acc[i][j] = __builtin_amdgcn_mfma_f32_16x16x32_f16(af[i], bf[j], acc[i][j], 0, 0, 0);
    }

    // ---- epilogue: C row = m0+wr+i*16+quad*4+r, col = n0+wc+j*16+lm ----
#pragma unroll
    for (int i = 0; i < 4; ++i) {
#pragma unroll
        for (int r = 0; r < 4; ++r) {
            const int m = m0 + wr + i * 16 + quad * 4 + r;
#pragma unroll
            for (int j = 0; j < 4; ++j) {
                const int n = n0 + wc + j * 16 + lm;
                float v = acc[i][j][r];
                if (RES) v += RES[(long long)m * ldres + n];
                C[(long long)m * ldc + n] = v;
            }
        }
    }
}

// ---------------- embedding dequant ----------------
__global__ __launch_bounds__(256) void embed_k(
    const int* __restrict__ ids, const int* __restrict__ eq,
    const float* __restrict__ es, const float* __restrict__ ez,
    float* __restrict__ h)
{
    const int t = blockIdx.x;
    const int id = ids[t];
    const float sc = es[id];
    const float zp = ez[id];
    const int* row = eq + (long long)id * Hdim;
    float* hr = h + (long long)t * Hdim;
    for (int c = threadIdx.x; c < Hdim; c += 256)
        hr[c] = (float)row[c] * sc + zp;
}

// ---------------- RMSNorm over rows of width W ----------------
__global__ __launch_bounds__(256) void rmsnorm_k(
    const float* __restrict__ x, const float* __restrict__ w,
    float* __restrict__ o, int W)
{
    const int row = blockIdx.x;
    const float* xr = x + (long long)row * W;
    float* orow = o + (long long)row * W;
    float ss = 0.f;
    for (int c = threadIdx.x; c < W; c += 256) { float v = xr[c]; ss += v * v; }
    __shared__ float red[256];
    red[threadIdx.x] = ss;
    __syncthreads();
    for (int s = 128; s > 0; s >>= 1) {
        if (threadIdx.x < s) red[threadIdx.x] += red[threadIdx.x + s];
        __syncthreads();
    }
    const float inv = 1.0f / sqrtf(red[0] / (float)W + EPS);
    for (int c = threadIdx.x; c < W; c += 256) orow[c] = xr[c] * inv * w[c];
}

// ---------------- RoPE + per-head RMS for q and k ----------------
__global__ __launch_bounds__(128) void rope_k(
    const float* __restrict__ qbuf,   // [Tq, Hdim]
    const float* __restrict__ kbuf,   // [Tq, KVH*HD]
    const float* __restrict__ q_ln,   // [HD]
    const float* __restrict__ k_ln,   // [HD]
    float* __restrict__ q_r,          // [NH, Tq, HD]
    float* __restrict__ nk)           // layer base of out nk: [KVH, HD, KVLEN]
{
    const int t = blockIdx.y;
    const int head = blockIdx.x;      // 0..NH+KVH-1
    const int d = threadIdx.x;        // 0..127
    const bool isq = head < NH;
    const float* in = isq ? &qbuf[(long long)t * Hdim + head * HD]
                          : &kbuf[(long long)t * (KVH * HD) + (head - NH) * HD];
    __shared__ float row[HD];
    row[d] = in[d];
    __syncthreads();
    const int j = d & 63;
    const float e = (float)j * (2.0f / 128.0f);
    const float inv_freq = 1.0f / powf(10000.0f, e);
    const float ang = (float)(HIST + t) * inv_freq;
    const float c = __half2float(__float2half(cosf(ang)));
    const float s = __half2float(__float2half(sinf(ang)));
    const float other = (d < 64) ? -row[d + 64] : row[d - 64];
    const float r = row[d] * c + other * s;
    __shared__ float red[HD];
    red[d] = r * r;
    __syncthreads();
    for (int st = 64; st > 0; st >>= 1) {
        if (d < st) red[d] += red[d + st];
        __syncthreads();
    }
    const float inv = 1.0f / sqrtf(red[0] / (float)HD + EPS);
    const float wv = (isq ? q_ln[d] : k_ln[d]) * SCALE_FACTOR;
    const float outv = r * inv * wv;
    if (isq) {
        q_r[((long long)head * Tq + t) * HD + d] = outv;
    } else {
        const int jh = head - NH;
        nk[((long long)jh * HD + d) * KVLEN + (HIST + t)] = outv;
    }
}

// ---------------- cache copies into outputs ----------------
__global__ __launch_bounds__(256) void kcache_copy_k(
    const float* __restrict__ kc, float* __restrict__ nk)
{
    const long long i = (long long)blockIdx.x * 256 + threadIdx.x; // < L*KVH*HD*HIST
    const long long row = i >> 10;       // /HIST
    const int c = (int)(i & 1023);
    nk[row * KVLEN + c] = kc[i];
}
__global__ __launch_bounds__(256) void vcache_copy_k(
    const float* __restrict__ vc, float* __restrict__ nv)
{
    const long long i = (long long)blockIdx.x * 256 + threadIdx.x; // < L*KVH*HIST*HD
    const long long chunk = i / (HIST * HD);
    const long long off = i % (HIST * HD);
    nv[chunk * (long long)(KVLEN * HD) + off] = vc[i];
}
// new v rows into nv layer base [KVH, KVLEN, HD]
__global__ __launch_bounds__(256) void vnew_copy_k(
    const float* __restrict__ vbuf, float* __restrict__ nv)
{
    const int i = blockIdx.x * 256 + threadIdx.x;   // < Tq*KVH*HD
    const int t = i >> 9;
    const int rem = i & 511;
    const int j = rem >> 7;
    const int d = rem & 127;
    nv[((long long)j * KVLEN + HIST + t) * HD + d] = vbuf[i];
}

// ---------------- mask + softmax over score rows ----------------
__global__ __launch_bounds__(256) void softmax_k(
    float* __restrict__ scores, const float* __restrict__ flagp)
{
    const int t = blockIdx.x;
    const int hh = blockIdx.y;
    float* row = scores + ((long long)hh * Tq + t) * KVLEN;
    const float maskv = -128.0f * flagp[0];
    float vals[5];
    float m = -INFINITY;
#pragma unroll
    for (int ii = 0; ii < 5; ++ii) {
        const int c = threadIdx.x + ii * 256;
        float v = row[c] + ((c <= t) ? 0.0f : maskv);
        vals[ii] = v;
        m = fmaxf(m, v);
    }
    __shared__ float red[256];
    red[threadIdx.x] = m;
    __syncthreads();
    for (int s = 128; s > 0; s >>= 1) {
        if (threadIdx.x < s) red[threadIdx.x] = fmaxf(red[threadIdx.x], red[threadIdx.x + s]);
        __syncthreads();
    }
    const float M = red[0];
    __syncthreads();
    float sum = 0.f;
#pragma unroll
    for (int ii = 0; ii < 5; ++ii) {
        const float ev = expf(vals[ii] - M);
        vals[ii] = ev;
        sum += ev;
    }
    red[threadIdx.x] = sum;
    __syncthreads();
    for (int s = 128; s > 0; s >>= 1) {
        if (threadIdx.x < s) red[threadIdx.x] += red[threadIdx.x + s];
        __syncthreads();
    }
    const float invS = 1.0f / red[0];
#pragma unroll
    for (int ii = 0; ii < 5; ++ii)
        row[threadIdx.x + ii * 256] = vals[ii] * invS;
}

// ---------------- SwiGLU elementwise ----------------
__global__ __launch_bounds__(256) void swiglu_k(
    float* __restrict__ gate, const float* __restrict__ up, long long n)
{
    const long long i = (long long)blockIdx.x * 256 + threadIdx.x;
    if (i < n) {
        const float g = gate[i];
        const float si = g / (1.0f + expf(-g));
        gate[i] = si * up[i];
    }
}

// ---------------- lm_head GEMV ----------------
__global__ __launch_bounds__(256) void lmhead_k(
    const float* __restrict__ hl, const float* __restrict__ W,
    float* __restrict__ logits)
{
    __shared__ float s_hl[Hdim];
    for (int k = threadIdx.x; k < Hdim; k += 256) s_hl[k] = hl[k];
    __syncthreads();
    const int col = blockIdx.x * 64 + (threadIdx.x & 63);
    const int kp = threadIdx.x >> 6;  // 0..3
    float acc = 0.f;
    for (int k = kp; k < Hdim; k += 4)
        acc = fmaf(s_hl[k], W[(long long)k * VOCAB + col], acc);
    __shared__ float red[256];
    red[threadIdx.x] = acc;
    __syncthreads();
    if (kp == 0)
        logits[col] = red[threadIdx.x] + red[threadIdx.x + 64] +
                      red[threadIdx.x + 128] + red[threadIdx.x + 192];
}

// ---------------- argmax (first-max tie-break) + KV scalar ----------------
__global__ __launch_bounds__(256) void argmax_k(
    const float* __restrict__ logits, float* __restrict__ out_tok,
    float* __restrict__ out_kv)
{
    float best = -INFINITY;
    int bi = 0x7fffffff;
    for (int c = threadIdx.x; c < VOCAB; c += 256) {
        const float v = logits[c];
        if (v > best) { best = v; bi = c; }
    }
    __shared__ float bv[256];
    __shared__ int bidx[256];
    bv[threadIdx.x] = best;
    bidx[threadIdx.x] = bi;
    __syncthreads();
    for (int s = 128; s > 0; s >>= 1) {
        if (threadIdx.x < s) {
            const float ov = bv[threadIdx.x + s];
            const int oi = bidx[threadIdx.x + s];
            if (ov > bv[threadIdx.x] ||
                (ov == bv[threadIdx.x] && oi < bidx[threadIdx.x])) {
                bv[threadIdx.x] = ov;
                bidx[threadIdx.x] = oi;
            }
        }
        __syncthreads();
    }
    if (threadIdx.x == 0) {
        out_tok[0] = (float)bidx[0];
        out_kv[0] = (float)KVLEN;
    }
}

// =======================================================================
extern "C" void kernel_launch(void* const* d_in, const int* in_sizes, int n_in,
                              void* d_out, int out_size, void* d_ws, size_t ws_size,
                              hipStream_t stream)
{
    // inputs (setup_inputs order)
    const int*   input_ids   = (const int*)  d_in[0];
    const float* key_cache   = (const float*)d_in[1];
    const float* value_cache = (const float*)d_in[2];
    const float* attn_flag   = (const float*)d_in[3];
    const int*   embed_q     = (const int*)  d_in[6];
    const float* embed_scale = (const float*)d_in[7];
    const float* embed_zp    = (const float*)d_in[8];
    const float* in_ln_w     = (const float*)d_in[9];
    const float* wq          = (const float*)d_in[10];
    const float* wk          = (const float*)d_in[11];
    const float* wv          = (const float*)d_in[12];
    const float* wo          = (const float*)d_in[13];
    const float* q_ln_w      = (const float*)d_in[14];
    const float* k_ln_w      = (const float*)d_in[15];
    const float* post_ln_w   = (const float*)d_in[16];
    const float* w_gate      = (const float*)d_in[17];
    const float* w_up        = (const float*)d_in[18];
    const float* w_down      = (const float*)d_in[19];
    const float* final_norm_w= (const float*)d_in[20];
    const float* lm_head_w   = (const float*)d_in[21];

    // outputs (flat fp32): nk | nv | token | kv
    float* out_nk = (float*)d_out;
    float* out_nv = out_nk + (long long)LAYERS * KVH * HD * KVLEN;
    float* out_tok = out_nv + (long long)LAYERS * KVH * KVLEN * HD;
    float* out_kv = out_tok + 1;

    // workspace layout (floats)
    float* ws = (float*)d_ws;
    float* h        = ws;                       // Tq*Hdim = 524288
    float* hn       = h + 524288;               // 524288
    float* qbuf     = hn + 524288;              // 524288
    float* q_r      = qbuf + 524288;            // 524288
    float* kbuf     = q_r + 524288;             // 131072
    float* vbuf     = kbuf + 131072;            // 131072
    float* attn_out = vbuf + 131072;            // 524288
    float* scores   = attn_out + 524288;        // NH*Tq*KVLEN = 5242880
    float* gate     = scores;                   // reuse (after attn@V)
    float* up       = scores + 2097152;         // reuse
    float* hl       = scores + 5242880;         // 2048
    float* logits   = hl + 2048;                // 32000

    dim3 b256(256);

    // embed -> h
    embed_k<<<dim3(Tq), b256, 0, stream>>>(input_ids, embed_q, embed_scale, embed_zp, h);

    // copy caches into outputs
    {
        const long long nk_tot = (long long)LAYERS * KVH * HD * HIST;  // 2097152
        kcache_copy_k<<<dim3((unsigned)((nk_tot + 255) / 256)), b256, 0, stream>>>(key_cache, out_nk);
        const long long nv_tot = (long long)LAYERS * KVH * HIST * HD;
        vcache_copy_k<<<dim3((unsigned)((nv_tot + 255) / 256)), b256, 0, stream>>>(value_cache, out_nv);
    }

    for (int l = 0; l < LAYERS; ++l) {
        const float* wq_l = wq + (long long)l * Hdim * Hdim;
        const float* wk_l = wk + (long long)l * Hdim * (KVH * HD);
        const float* wv_l = wv + (long long)l * Hdim * (KVH * HD);
        const float* wo_l = wo + (long long)l * Hdim * Hdim;
        const float* wg_l = w_gate + (long long)l * Hdim * FF;
        const float* wu_l = w_up + (long long)l * Hdim * FF;
        const float* wd_l = w_down + (long long)l * FF * Hdim;
        float* nk_l = out_nk + (long long)l * KVH * HD * KVLEN;
        float* nv_l = out_nv + (long long)l * KVH * KVLEN * HD;

        // hn = rms(h, in_ln_w[l])
        rmsnorm_k<<<dim3(Tq), b256, 0, stream>>>(h, in_ln_w + (long long)l * Hdim, hn, Hdim);

        // q/k/v projections (MFMA)
        gemm_mfma<<<dim3(Hdim / BN, Tq / BM, 1), b256, 0, stream>>>(
            hn, Hdim, 0, wq_l, Hdim, 0, 1, qbuf, Hdim, 0, nullptr, 0, Hdim);
        gemm_mfma<<<dim3((KVH * HD) / BN, Tq / BM, 1), b256, 0, stream>>>(
            hn, Hdim, 0, wk_l, KVH * HD, 0, 1, kbuf, KVH * HD, 0, nullptr, 0, Hdim);
        gemm_mfma<<<dim3((KVH * HD) / BN, Tq / BM, 1), b256, 0, stream>>>(
            hn, Hdim, 0, wv_l, KVH * HD, 0, 1, vbuf, KVH * HD, 0, nullptr, 0, Hdim);

        // rope + head-RMS; k written transposed into out nk
        rope_k<<<dim3(NH + KVH, Tq), dim3(128), 0, stream>>>(
            qbuf, kbuf, q_ln_w + (long long)l * HD, k_ln_w + (long long)l * HD, q_r, nk_l);

        // new v rows into out nv
        vnew_copy_k<<<dim3((Tq * KVH * HD) / 256), b256, 0, stream>>>(vbuf, nv_l);

        // scores[h] = q_r[h] (Tq x HD) @ nk[h/G] (HD x KVLEN)
        gemm_mfma<<<dim3(KVLEN / BN, Tq / BM, NH), b256, 0, stream>>>(
            q_r, HD, (long long)Tq * HD,
            nk_l, KVLEN, (long long)HD * KVLEN, GQA,
            scores, KVLEN, (long long)Tq * KVLEN,
            nullptr, 0, HD);

        // mask + softmax
        softmax_k<<<dim3(Tq, NH), b256, 0, stream>>>(scores, attn_flag);

        // attn_out[:, h*HD:(h+1)*HD] = P[h] (Tq x KVLEN) @ nv[h/G] (KVLEN x HD)
        gemm_mfma<<<dim3(HD / BN, Tq / BM, NH), b256, 0, stream>>>(
            scores, KVLEN, (long long)Tq * KVLEN,
            nv_l, HD, (long long)KVLEN * HD, GQA,
            attn_out, Hdim, (long long)HD,
            nullptr, 0, KVLEN);

        // h = h + attn_out @ wo
        gemm_mfma<<<dim3(Hdim / BN, Tq / BM, 1), b256, 0, stream>>>(
            attn_out, Hdim, 0, wo_l, Hdim, 0, 1, h, Hdim, 0, h, Hdim, Hdim);

        // post-LN
        rmsnorm_k<<<dim3(Tq), b256, 0, stream>>>(h, post_ln_w + (long long)l * Hdim, hn, Hdim);

        // gate / up
        gemm_mfma<<<dim3(FF / BN, Tq / BM, 1), b256, 0, stream>>>(
            hn, Hdim, 0, wg_l, FF, 0, 1, gate, FF, 0, nullptr, 0, Hdim);
        gemm_mfma<<<dim3(FF / BN, Tq / BM, 1), b256, 0, stream>>>(
            hn, Hdim, 0, wu_l, FF, 0, 1, up, FF, 0, nullptr, 0, Hdim);

        // gate = silu(gate)*up
        swiglu_k<<<dim3((Tq * FF) / 256), b256, 0, stream>>>(gate, up, (long long)Tq * FF);

        // h = h + gate @ w_down
        gemm_mfma<<<dim3(Hdim / BN, Tq / BM, 1), b256, 0, stream>>>(
            gate, FF, 0, wd_l, Hdim, 0, 1, h, Hdim, 0, h, Hdim, FF);
    }

    // final norm on last token
    rmsnorm_k<<<dim3(1), b256, 0, stream>>>(h + (long long)(Tq - 1) * Hdim, final_norm_w, hl, Hdim);

    // logits + argmax
    lmhead_k<<<dim3(VOCAB / 64), b256, 0, stream>>>(hl, lm_head_w, logits);
    argmax_k<<<dim3(1), b256, 0, stream>>>(logits, out_tok, out_kv);
}